// Round 1
// baseline (1188.371 us; speedup 1.0000x reference)
//
#include <hip/hip_runtime.h>

#define NUM_EMBED 8192
#define DIMC 64
#define HW 4096            // 64*64
#define NQ 32768           // 8*64*64
#define NWAVES 8
#define KSLICE (NUM_EMBED / NWAVES)   // 1024
#define TILE 32            // codes staged per tile
#define NTILES (KSLICE / TILE)        // 32

#define ZQ_SIZE  2097152
#define LOSS_OFF 2097152
#define IDX_OFF  2097153
#define BIN_OFF  2129921   // 2097153 + 32768

// --- Kernel 1: L2-normalize codebook rows into ws (cn) -----------------
__global__ void vq_prep(const float* __restrict__ ew, float* __restrict__ cn) {
    const int lane = threadIdx.x & 63;
    const int wave = threadIdx.x >> 6;
    const int row  = blockIdx.x * 4 + wave;      // 2048 blocks * 4 rows
    float v = ew[row * DIMC + lane];
    float s = v * v;
    #pragma unroll
    for (int off = 1; off < 64; off <<= 1) s += __shfl_xor(s, off, 64);
    float nrm = sqrtf(s);
    cn[row * DIMC + lane] = v / fmaxf(nrm, 1e-12f);
}

// --- Kernel 2: zero loss + bincount region of d_out --------------------
__global__ void vq_zero(float* __restrict__ out) {
    int i = blockIdx.x * 256 + threadIdx.x;
    if (i == 0) out[LOSS_OFF] = 0.0f;
    if (i < NUM_EMBED) out[BIN_OFF + i] = 0.0f;
}

// --- Kernel 3: main — argmax over codes + epilogue ---------------------
__global__ __launch_bounds__(512) void vq_main(
    const float* __restrict__ z, const float* __restrict__ ew,
    const float* __restrict__ cn, float* __restrict__ out)
{
    __shared__ float tile[NWAVES][TILE * DIMC];   // 8 * 8 KB = 64 KB
    __shared__ float cbest[NWAVES][64];
    __shared__ int   cidx[NWAVES][64];

    const int lane = threadIdx.x & 63;
    const int wave = threadIdx.x >> 6;
    const int q    = blockIdx.x * 64 + lane;      // query index (n)
    const int b    = q >> 12;                     // / 4096
    const int hw   = q & 4095;
    const float* zp = z + (size_t)b * (DIMC * HW) + hw;

    // load this thread's query vector (coalesced across lanes per channel)
    float zf[DIMC];
    #pragma unroll
    for (int c = 0; c < DIMC; ++c) zf[c] = zp[(size_t)c * HW];

    float best = -3.0e38f;
    int   bidx = 0;
    const int kbase = wave * KSLICE;
    float* myTile = tile[wave];

    for (int t = 0; t < NTILES; ++t) {
        // stage 32 codes (8 KB) into this wave's private LDS region.
        // wave-synchronous: no __syncthreads needed; compiler inserts waits.
        const float4* src = (const float4*)(cn + (size_t)(kbase + t * TILE) * DIMC);
        #pragma unroll
        for (int i = 0; i < (TILE * DIMC / 4) / 64; ++i) {   // 8 iters
            ((float4*)myTile)[i * 64 + lane] = src[i * 64 + lane];
        }
        for (int k = 0; k < TILE; ++k) {
            const float* row = &myTile[k * DIMC];   // same addr all lanes -> LDS broadcast
            float a0 = 0.f, a1 = 0.f, a2 = 0.f, a3 = 0.f;
            #pragma unroll
            for (int j = 0; j < DIMC; j += 4) {     // 4 independent FMA chains
                a0 = fmaf(row[j + 0], zf[j + 0], a0);
                a1 = fmaf(row[j + 1], zf[j + 1], a1);
                a2 = fmaf(row[j + 2], zf[j + 2], a2);
                a3 = fmaf(row[j + 3], zf[j + 3], a3);
            }
            float d = (a0 + a1) + (a2 + a3);
            int kk = kbase + t * TILE + k;
            if (d > best) { best = d; bidx = kk; }  // strict > keeps first max
        }
    }

    cbest[wave][lane] = best;
    cidx[wave][lane]  = bidx;
    __syncthreads();

    if (wave == 0) {
        float fb = cbest[0][lane];
        int   fi = cidx[0][lane];
        #pragma unroll
        for (int w2 = 1; w2 < NWAVES; ++w2) {       // ascending slice order:
            float v = cbest[w2][lane];              // strict > preserves
            int  ii = cidx[w2][lane];               // lowest-index tie-break
            if (v > fb) { fb = v; fi = ii; }
        }

        // idx (as float)
        out[IDX_OFF + q] = (float)fi;
        // bincount (float atomic, counts are small integers -> exact)
        atomicAdd(&out[BIN_OFF + fi], 1.0f);

        // z_q scatter (b,c,h,w layout) + loss partial
        const float* wrow = ew + (size_t)fi * DIMC;
        float* zq = out + (size_t)b * (DIMC * HW) + hw;
        float lsum = 0.f;
        #pragma unroll
        for (int c = 0; c < DIMC; ++c) {
            float wv = wrow[c];
            zq[(size_t)c * HW] = wv;                // coalesced per channel
            float dd = wv - zf[c];
            lsum = fmaf(dd, dd, lsum);
        }
        // wave-reduce loss, one atomic per block
        #pragma unroll
        for (int off = 32; off; off >>= 1) lsum += __shfl_down(lsum, off, 64);
        if (lane == 0)
            atomicAdd(&out[LOSS_OFF], lsum * (1.25f / (float)ZQ_SIZE));
    }
}

extern "C" void kernel_launch(void* const* d_in, const int* in_sizes, int n_in,
                              void* d_out, int out_size, void* d_ws, size_t ws_size,
                              hipStream_t stream) {
    const float* z  = (const float*)d_in[0];        // [8,64,64,64] f32
    const float* ew = (const float*)d_in[1];        // [8192,64] f32
    float* out = (float*)d_out;
    float* cn  = (float*)d_ws;                      // 2 MB normalized codebook

    vq_prep<<<NUM_EMBED / 4, 256, 0, stream>>>(ew, cn);
    vq_zero<<<(NUM_EMBED + 255) / 256, 256, 0, stream>>>(out);
    vq_main<<<NQ / 64, 512, 0, stream>>>(z, ew, cn, out);
}

// Round 2
// 618.539 us; speedup vs baseline: 1.9213x; 1.9213x over previous
//
#include <hip/hip_runtime.h>

#define NUM_EMBED 8192
#define DIMC 64
#define HW 4096            // 64*64
#define NQ 32768           // 8*64*64
#define NWAVES 8
#define KSLICE (NUM_EMBED / NWAVES)   // 1024 codes per wave

#define ZQ_SIZE  2097152
#define LOSS_OFF 2097152
#define IDX_OFF  2097153
#define BIN_OFF  2129921   // 2097153 + 32768

// --- Kernel 1: L2-normalize codebook rows into ws (cn) -----------------
__global__ void vq_prep(const float* __restrict__ ew, float* __restrict__ cn) {
    const int lane = threadIdx.x & 63;
    const int wave = threadIdx.x >> 6;
    const int row  = blockIdx.x * 4 + wave;      // 2048 blocks * 4 rows
    float v = ew[row * DIMC + lane];
    float s = v * v;
    #pragma unroll
    for (int off = 1; off < 64; off <<= 1) s += __shfl_xor(s, off, 64);
    float nrm = sqrtf(s);
    cn[row * DIMC + lane] = v / fmaxf(nrm, 1e-12f);
}

// --- Kernel 2: zero loss + bincount region of d_out --------------------
__global__ void vq_zero(float* __restrict__ out) {
    int i = blockIdx.x * 256 + threadIdx.x;
    if (i == 0) out[LOSS_OFF] = 0.0f;
    if (i < NUM_EMBED) out[BIN_OFF + i] = 0.0f;
}

// --- Kernel 3: main — argmax over codes via SGPR-broadcast codes -------
// Codes are wave-uniform -> scalar (SMEM) loads; zero LDS in the hot loop.
__global__ __launch_bounds__(512) void vq_main(
    const float* __restrict__ z, const float* __restrict__ ew,
    const float* __restrict__ cn, float* __restrict__ out)
{
    __shared__ float cbest[NWAVES][64];
    __shared__ int   cidx[NWAVES][64];

    const int lane = threadIdx.x & 63;
    const int wave = threadIdx.x >> 6;
    const int q    = blockIdx.x * 64 + lane;      // query index (n)
    const int b    = q >> 12;                     // / 4096
    const int hw   = q & 4095;
    const float* zp = z + (size_t)b * (DIMC * HW) + hw;

    // this thread's query vector (coalesced per channel across lanes)
    float zf[DIMC];
    #pragma unroll
    for (int c = 0; c < DIMC; ++c) zf[c] = zp[(size_t)c * HW];

    // wave-uniform code-slice base, forced into an SGPR so the compiler's
    // uniformity analysis scalarizes the code-row loads (s_load_dwordx16).
    const int kbaseU = __builtin_amdgcn_readfirstlane(wave * KSLICE);

    float best = -3.0e38f;
    int   bidx = 0;

    #pragma unroll 1
    for (int k = 0; k < KSLICE; ++k) {
        const float* __restrict__ row = cn + (size_t)(kbaseU + k) * DIMC;
        float a0 = 0.f, a1 = 0.f, a2 = 0.f, a3 = 0.f;
        #pragma unroll
        for (int j = 0; j < DIMC; j += 4) {       // 4 independent FMA chains
            a0 = fmaf(row[j + 0], zf[j + 0], a0); // v_fmac v, s, v
            a1 = fmaf(row[j + 1], zf[j + 1], a1);
            a2 = fmaf(row[j + 2], zf[j + 2], a2);
            a3 = fmaf(row[j + 3], zf[j + 3], a3);
        }
        float d = (a0 + a1) + (a2 + a3);
        int kk = kbaseU + k;
        if (d > best) { best = d; bidx = kk; }    // strict > keeps first max
    }

    cbest[wave][lane] = best;
    cidx[wave][lane]  = bidx;
    __syncthreads();

    if (wave == 0) {
        float fb = cbest[0][lane];
        int   fi = cidx[0][lane];
        #pragma unroll
        for (int w2 = 1; w2 < NWAVES; ++w2) {     // ascending slice order:
            float v = cbest[w2][lane];            // strict > preserves
            int  ii = cidx[w2][lane];             // lowest-index tie-break
            if (v > fb) { fb = v; fi = ii; }
        }

        // idx (as float)
        out[IDX_OFF + q] = (float)fi;
        // bincount (float atomic, small integer counts -> exact)
        atomicAdd(&out[BIN_OFF + fi], 1.0f);

        // z_q scatter (b,c,h,w layout) + loss partial
        const float* wrow = ew + (size_t)fi * DIMC;
        float* zq = out + (size_t)b * (DIMC * HW) + hw;
        float lsum = 0.f;
        #pragma unroll
        for (int c = 0; c < DIMC; ++c) {
            float wv = wrow[c];
            zq[(size_t)c * HW] = wv;              // coalesced per channel
            float dd = wv - zf[c];
            lsum = fmaf(dd, dd, lsum);
        }
        // wave-reduce loss, one atomic per block
        #pragma unroll
        for (int off = 32; off; off >>= 1) lsum += __shfl_down(lsum, off, 64);
        if (lane == 0)
            atomicAdd(&out[LOSS_OFF], lsum * (1.25f / (float)ZQ_SIZE));
    }
}

extern "C" void kernel_launch(void* const* d_in, const int* in_sizes, int n_in,
                              void* d_out, int out_size, void* d_ws, size_t ws_size,
                              hipStream_t stream) {
    const float* z  = (const float*)d_in[0];        // [8,64,64,64] f32
    const float* ew = (const float*)d_in[1];        // [8192,64] f32
    float* out = (float*)d_out;
    float* cn  = (float*)d_ws;                      // 2 MB normalized codebook

    vq_prep<<<NUM_EMBED / 4, 256, 0, stream>>>(ew, cn);
    vq_zero<<<(NUM_EMBED + 255) / 256, 256, 0, stream>>>(out);
    vq_main<<<NQ / 64, 512, 0, stream>>>(z, ew, cn, out);
}

// Round 3
// 306.633 us; speedup vs baseline: 3.8755x; 2.0172x over previous
//
#include <hip/hip_runtime.h>

#define NUM_EMBED 8192
#define DIMC 64
#define HW 4096
#define NQ 32768
#define ZQ_SIZE  2097152
#define LOSS_OFF 2097152
#define IDX_OFF  2097153
#define BIN_OFF  2129921
#define EPS 1e-3f

// ws layout (bytes)
#define WS_B      0           // ushort[8192*128]  codes: [ch(64) | cl(64)] per row
#define WS_INV    2097152     // float[8192]       1/max(||ew_k||,1e-12)
#define WS_CNT    2129920     // int               uncertain-count
#define WS_LIST   2129936     // int[32768]        uncertain query list

typedef unsigned int  uint;
typedef unsigned short ushort;
typedef __attribute__((ext_vector_type(8))) short short8;   // bf16x8 MFMA frag
typedef __attribute__((ext_vector_type(4))) float float4_;
typedef __attribute__((ext_vector_type(4))) uint  uint4_;

__device__ inline ushort f2bf(float f) {            // fp32 -> bf16 RTNE
    uint u = __float_as_uint(f);
    return (ushort)((u + 0x7FFFu + ((u >> 16) & 1u)) >> 16);
}
__device__ inline float bf2f(ushort h) { return __uint_as_float(((uint)h) << 16); }

// --- prep: normalize codebook, split to bf16 hi/lo, store inv-norms --------
__global__ __launch_bounds__(256) void vq_prep_b(const float* __restrict__ ew,
        ushort* __restrict__ Bp, float* __restrict__ invn)
{
    const int ln  = threadIdx.x & 63;
    const int wv  = threadIdx.x >> 6;
    const int row = blockIdx.x * 4 + wv;
    float v = ew[row * 64 + ln];
    float s = v * v;
    #pragma unroll
    for (int off = 1; off < 64; off <<= 1) s += __shfl_xor(s, off, 64);
    float rinv = 1.0f / fmaxf(sqrtf(s), 1e-12f);
    float cn = v * rinv;
    ushort hi = f2bf(cn);
    ushort lo = f2bf(cn - bf2f(hi));
    Bp[row * 128 + ln]      = hi;
    Bp[row * 128 + 64 + ln] = lo;
    if (ln == 0) invn[row] = rinv;
}

// --- zero loss / bins / uncertain-count ------------------------------------
__global__ void vq_zero(float* __restrict__ out, int* __restrict__ cnt) {
    int i = blockIdx.x * 256 + threadIdx.x;
    if (i == 0) { out[LOSS_OFF] = 0.0f; *cnt = 0; }
    if (i < NUM_EMBED) out[BIN_OFF + i] = 0.0f;
}

// --- main: split-bf16 MFMA scores + fused streaming top-2 ------------------
// 256 blocks x 256 thr. Block owns 128 queries, loops 64 code-tiles of 128.
__global__ __launch_bounds__(256, 1) void vq_main(const float* __restrict__ z,
        const ushort* __restrict__ Bp, float* __restrict__ out,
        int* __restrict__ cnt, int* __restrict__ list)
{
    __shared__ __align__(16) ushort qtile[128 * 136];      // rows padded to 136
    __shared__ __align__(16) ushort ctile[2][128 * 136];   // double-buffered

    const int tid = threadIdx.x;
    const int ln  = tid & 63;
    const int wv  = tid >> 6;          // 0..3
    const int wq  = wv >> 1, wc = wv & 1;
    const int lm  = ln & 15;           // tile-local row/col
    const int h   = ln >> 4;           // 0..3
    const int h8  = h * 8;

    const int q0  = blockIdx.x * 128;
    const int b   = q0 >> 12;
    const int hw0 = q0 & 4095;

    // build query tile: [q][c]=zh, [q][64+c]=zl
    {
        const int t128 = tid & 127;
        const int coff = tid >> 7;
        const float* zb = z + (size_t)b * (DIMC * HW) + hw0 + t128;
        for (int ci = 0; ci < 32; ++ci) {
            int c = ci * 2 + coff;
            float f = zb[(size_t)c * HW];
            ushort hi = f2bf(f);
            ushort lo = f2bf(f - bf2f(hi));
            qtile[t128 * 136 + c]      = hi;
            qtile[t128 * 136 + 64 + c] = lo;
        }
    }

    // code-tile staging (VGPR round-trip so rows can be padded)
    const int srow = tid >> 1;
    const int sch  = (tid & 1) * 8;
    uint4_ sv[8];
    auto stage_load = [&](int tt) {
        const uint4_* g = (const uint4_*)(Bp + (size_t)(tt * 128 + srow) * 128);
        #pragma unroll
        for (int c2 = 0; c2 < 8; ++c2) sv[c2] = g[sch + c2];
    };
    auto stage_write = [&](int bf) {
        #pragma unroll
        for (int c2 = 0; c2 < 8; ++c2)
            *(uint4_*)&ctile[bf][srow * 136 + (sch + c2) * 8] = sv[c2];
    };

    stage_load(0); stage_write(0);
    stage_load(1);
    __syncthreads();

    // query fragments -> registers (live for whole kernel)
    short8 qh0[4], qh1[4], ql0[4], ql1[4];
    #pragma unroll
    for (int qt = 0; qt < 4; ++qt) {
        const ushort* r = &qtile[(wq * 64 + qt * 16 + lm) * 136 + h8];
        qh0[qt] = *(const short8*)(r);
        qh1[qt] = *(const short8*)(r + 32);
        ql0[qt] = *(const short8*)(r + 64);
        ql1[qt] = *(const short8*)(r + 96);
    }

    float v1[4], v2[4]; int i1[4];
    #pragma unroll
    for (int qt = 0; qt < 4; ++qt) { v1[qt] = -3e38f; v2[qt] = -3e38f; i1[qt] = 0; }

    for (int t = 0; t < 64; ++t) {
        const int p = t & 1;
        if (t + 1 < 64) stage_write(1 - p);   // tile t+1 -> other buffer
        if (t + 2 < 64) stage_load(t + 2);    // prefetch tile t+2

        float4_ acc[4][4];
        #pragma unroll
        for (int qt = 0; qt < 4; ++qt)
            #pragma unroll
            for (int cc = 0; cc < 4; ++cc) acc[qt][cc] = (float4_){0.f, 0.f, 0.f, 0.f};

        #pragma unroll
        for (int cc = 0; cc < 4; ++cc) {
            const ushort* r = &ctile[p][(wc * 64 + cc * 16 + lm) * 136 + h8];
            short8 ch0 = *(const short8*)(r);
            short8 ch1 = *(const short8*)(r + 32);
            short8 cl0 = *(const short8*)(r + 64);
            short8 cl1 = *(const short8*)(r + 96);
            #pragma unroll
            for (int qt = 0; qt < 4; ++qt) {
                float4_ a = acc[qt][cc];
                a = __builtin_amdgcn_mfma_f32_16x16x32_bf16(ch0, qh0[qt], a, 0, 0, 0);
                a = __builtin_amdgcn_mfma_f32_16x16x32_bf16(ch1, qh1[qt], a, 0, 0, 0);
                a = __builtin_amdgcn_mfma_f32_16x16x32_bf16(cl0, qh0[qt], a, 0, 0, 0);
                a = __builtin_amdgcn_mfma_f32_16x16x32_bf16(cl1, qh1[qt], a, 0, 0, 0);
                a = __builtin_amdgcn_mfma_f32_16x16x32_bf16(ch0, ql0[qt], a, 0, 0, 0);
                a = __builtin_amdgcn_mfma_f32_16x16x32_bf16(ch1, ql1[qt], a, 0, 0, 0);
                acc[qt][cc] = a;
            }
        }

        // streaming exact top-2 (C/D map: col=lane&15=query, row=h*4+reg=code)
        const int cb = t * 128 + wc * 64 + h * 4;
        #pragma unroll
        for (int cc = 0; cc < 4; ++cc)
            #pragma unroll
            for (int rr = 0; rr < 4; ++rr) {
                int code = cb + cc * 16 + rr;
                #pragma unroll
                for (int qt = 0; qt < 4; ++qt) {
                    float v = acc[qt][cc][rr];
                    bool gt = v > v1[qt];
                    v2[qt] = fmaxf(v2[qt], gt ? v1[qt] : v);
                    v1[qt] = gt ? v : v1[qt];
                    i1[qt] = gt ? code : i1[qt];
                }
            }
        __syncthreads();
    }

    // merge across h-groups (disjoint code rows, same query col)
    #pragma unroll
    for (int m = 16; m <= 32; m <<= 1) {
        #pragma unroll
        for (int qt = 0; qt < 4; ++qt) {
            float ov1 = __shfl_xor(v1[qt], m, 64);
            int   oi1 = __shfl_xor(i1[qt], m, 64);
            float ov2 = __shfl_xor(v2[qt], m, 64);
            float nv2 = fmaxf(fminf(v1[qt], ov1), fmaxf(v2[qt], ov2));
            bool tk = ov1 > v1[qt];
            v1[qt] = tk ? ov1 : v1[qt];
            i1[qt] = tk ? oi1 : i1[qt];
            v2[qt] = nv2;
        }
    }

    // cross-wc merge via LDS scratch (alias qtile; only needed post-loop)
    float* sc = (float*)qtile;
    if (h == 0) {
        #pragma unroll
        for (int qt = 0; qt < 4; ++qt) {
            int ql = wq * 64 + qt * 16 + lm;
            int o = (wc * 128 + ql) * 3;
            sc[o] = v1[qt]; ((int*)sc)[o + 1] = i1[qt]; sc[o + 2] = v2[qt];
        }
    }
    __syncthreads();
    if (tid < 128) {
        int oa = tid * 3, ob = (128 + tid) * 3;
        float a1 = sc[oa], a2 = sc[oa + 2]; int ai = ((int*)sc)[oa + 1];
        float b1 = sc[ob], b2 = sc[ob + 2]; int bi = ((int*)sc)[ob + 1];
        float nv2 = fmaxf(fminf(a1, b1), fmaxf(a2, b2));
        bool tk = b1 > a1;
        float fv1 = tk ? b1 : a1; int fi = tk ? bi : ai;
        int q = q0 + tid;
        out[IDX_OFF + q] = (float)fi;
        if (fv1 - nv2 <= EPS) {          // not provably exact -> rescan
            int s = atomicAdd(cnt, 1);
            list[s] = q;
        }
    }
}

// --- exact fp32 rescan for uncertain queries (expected ~100-300) -----------
__global__ __launch_bounds__(64) void vq_rescan(const float* __restrict__ z,
        const float* __restrict__ ew, const float* __restrict__ invn,
        const int* __restrict__ cnt, const int* __restrict__ list,
        float* __restrict__ out)
{
    const int ln = threadIdx.x;
    const int n = *cnt;
    for (int u = blockIdx.x; u < n; u += gridDim.x) {
        int q = list[u];
        int b = q >> 12, hw = q & 4095;
        const float* zp = z + (size_t)b * (DIMC * HW) + hw;
        float zf[64];
        #pragma unroll
        for (int c = 0; c < 64; ++c) zf[c] = zp[(size_t)c * HW];
        float best = -3e38f; int bi = 0;
        for (int j = 0; j < 128; ++j) {
            int k = j * 64 + ln;
            const float4_* row = (const float4_*)(ew + (size_t)k * 64);
            float a0 = 0.f, a1 = 0.f, a2 = 0.f, a3 = 0.f;
            #pragma unroll
            for (int c4 = 0; c4 < 16; ++c4) {
                float4_ rv = row[c4];
                a0 = fmaf(rv[0], zf[c4 * 4 + 0], a0);
                a1 = fmaf(rv[1], zf[c4 * 4 + 1], a1);
                a2 = fmaf(rv[2], zf[c4 * 4 + 2], a2);
                a3 = fmaf(rv[3], zf[c4 * 4 + 3], a3);
            }
            float d = ((a0 + a1) + (a2 + a3)) * invn[k];
            if (d > best) { best = d; bi = k; }
        }
        #pragma unroll
        for (int m = 1; m < 64; m <<= 1) {   // first-index tie-break
            float ov = __shfl_xor(best, m, 64);
            int   oi = __shfl_xor(bi, m, 64);
            if (ov > best || (ov == best && oi < bi)) { best = ov; bi = oi; }
        }
        if (ln == 0) out[IDX_OFF + q] = (float)bi;
    }
}

// --- emit z_q, loss, bincount from final idx -------------------------------
__global__ __launch_bounds__(64) void vq_emit(const float* __restrict__ z,
        const float* __restrict__ ew, float* __restrict__ out)
{
    const int ln = threadIdx.x;
    const int q  = blockIdx.x * 64 + ln;
    const int b  = q >> 12, hw = q & 4095;
    const float* zp = z + (size_t)b * (DIMC * HW) + hw;
    int idx = (int)out[IDX_OFF + q];
    atomicAdd(&out[BIN_OFF + idx], 1.0f);
    const float* wrow = ew + (size_t)idx * DIMC;
    float* zq = out + (size_t)b * (DIMC * HW) + hw;
    float lsum = 0.f;
    #pragma unroll
    for (int c = 0; c < DIMC; ++c) {
        float wvv = wrow[c];
        float zv  = zp[(size_t)c * HW];
        zq[(size_t)c * HW] = wvv;
        float dd = wvv - zv;
        lsum = fmaf(dd, dd, lsum);
    }
    #pragma unroll
    for (int off = 32; off; off >>= 1) lsum += __shfl_down(lsum, off, 64);
    if (ln == 0) atomicAdd(&out[LOSS_OFF], lsum * (1.25f / (float)ZQ_SIZE));
}

extern "C" void kernel_launch(void* const* d_in, const int* in_sizes, int n_in,
                              void* d_out, int out_size, void* d_ws, size_t ws_size,
                              hipStream_t stream) {
    const float* z  = (const float*)d_in[0];
    const float* ew = (const float*)d_in[1];
    float* out = (float*)d_out;
    char* ws = (char*)d_ws;
    ushort* Bp  = (ushort*)(ws + WS_B);
    float* invn = (float*)(ws + WS_INV);
    int* cnt    = (int*)(ws + WS_CNT);
    int* list   = (int*)(ws + WS_LIST);

    vq_prep_b<<<NUM_EMBED / 4, 256, 0, stream>>>(ew, Bp, invn);
    vq_zero<<<32, 256, 0, stream>>>(out, cnt);
    vq_main<<<NQ / 128, 256, 0, stream>>>(z, Bp, out, cnt, list);
    vq_rescan<<<256, 64, 0, stream>>>(z, ew, invn, cnt, list, out);
    vq_emit<<<NQ / 64, 64, 0, stream>>>(z, ew, out);
}